// Round 5
// baseline (160.972 us; speedup 1.0000x reference)
//
#include <hip/hip_runtime.h>

// CompositionalEmbeddings: out[b,s, 0:512]   = token_table[id]
//                          out[b,s, 512:1024] = cat_table[id]
// cat_table = concat(op[10], var[10], const[10], struct[10], special[49960]);
// category offsets align with id ranges -> direct gather.
//
// Round 5: bucket tokens by id (196 buckets of 256 ids) with a cheap
// counting pass, then run the gather in bucket order. Table reads become a
// near-sequential sweep with L2/L3 hits on repeated ids (~1.8x reuse),
// instead of random 2KB granules over 200MB. Writes stay 4KB-contiguous
// per token (NT). Processing order permutation doesn't change the output.

typedef float f32x4 __attribute__((ext_vector_type(4)));

#define V4_PER_HALF 128      // 512 floats / 4
#define BUCKET_SHIFT 8       // bucket = id >> 8  (256 ids per bucket)
#define NB 196               // ceil(50000 / 256)

// ---- prep kernels -------------------------------------------------------

__global__ __launch_bounds__(256) void k_zero(int* __restrict__ hist) {
    if (threadIdx.x < NB) hist[threadIdx.x] = 0;
}

__global__ __launch_bounds__(256) void k_hist(const int* __restrict__ ids,
                                              int* __restrict__ hist, int n) {
    int i = blockIdx.x * 256 + threadIdx.x;
    if (i < n) atomicAdd(&hist[ids[i] >> BUCKET_SHIFT], 1);
}

__global__ __launch_bounds__(256) void k_scan(const int* __restrict__ hist,
                                              int* __restrict__ offs) {
    // exclusive scan over NB<=256 bins, one block
    __shared__ int s[256];
    int t = threadIdx.x;
    int v = (t < NB) ? hist[t] : 0;
    s[t] = v;
    __syncthreads();
    for (int d = 1; d < 256; d <<= 1) {
        int x = (t >= d) ? s[t - d] : 0;
        __syncthreads();
        s[t] += x;
        __syncthreads();
    }
    if (t < NB) offs[t] = s[t] - v;   // exclusive
}

__global__ __launch_bounds__(256) void k_scatter(const int* __restrict__ ids,
                                                 int* __restrict__ offs,
                                                 int* __restrict__ perm, int n) {
    int i = blockIdx.x * 256 + threadIdx.x;
    if (i < n) {
        int pos = atomicAdd(&offs[ids[i] >> BUCKET_SHIFT], 1);
        perm[pos] = i;
    }
}

// ---- main gather --------------------------------------------------------

__global__ __launch_bounds__(256) void compemb_kernel(
    const int* __restrict__ perm,
    const int* __restrict__ ids,
    const f32x4* __restrict__ tok,     // [50000][128]
    const f32x4* __restrict__ op_t,    // [10][128]
    const f32x4* __restrict__ var_t,   // [10][128]
    const f32x4* __restrict__ cst_t,   // [10][128]
    const f32x4* __restrict__ str_t,   // [10][128]
    const f32x4* __restrict__ spc_t,   // [49960][128]
    f32x4* __restrict__ out)           // [n_tokens][256]
{
    const int token = perm[blockIdx.x];   // bucket-sorted processing order
    const int id = ids[token];            // block-uniform
    const int t  = threadIdx.x;
    const int e  = t & (V4_PER_HALF - 1);

    const f32x4* src;
    long long row;
    if (t < V4_PER_HALF) {
        src = tok;  row = id;             // waves 0-1: token half
    } else {
        if (id < 10)      { src = op_t;  row = id; }       // waves 2-3
        else if (id < 20) { src = var_t; row = id - 10; }
        else if (id < 30) { src = cst_t; row = id - 20; }
        else if (id < 40) { src = str_t; row = id - 30; }
        else              { src = spc_t; row = id - 40; }
    }

    const f32x4 v = src[row * V4_PER_HALF + e];
    __builtin_nontemporal_store(v, &out[(long long)token * 256 + t]);
}

// ---- launch -------------------------------------------------------------

extern "C" void kernel_launch(void* const* d_in, const int* in_sizes, int n_in,
                              void* d_out, int out_size, void* d_ws, size_t ws_size,
                              hipStream_t stream) {
    const int*   ids   = (const int*)  d_in[0];
    const f32x4* tok   = (const f32x4*)d_in[1];
    const f32x4* op_t  = (const f32x4*)d_in[2];
    const f32x4* var_t = (const f32x4*)d_in[3];
    const f32x4* cst_t = (const f32x4*)d_in[4];
    const f32x4* str_t = (const f32x4*)d_in[5];
    const f32x4* spc_t = (const f32x4*)d_in[6];
    f32x4* out = (f32x4*)d_out;

    const int n_tokens = in_sizes[0];          // 65536

    // workspace layout: [0..NB) hist, [256..256+NB) offs, [512..512+n) perm
    int* hist = (int*)d_ws;
    int* offs = hist + 256;
    int* perm = hist + 512;

    const int nblk = (n_tokens + 255) / 256;
    k_zero   <<<1,    256, 0, stream>>>(hist);
    k_hist   <<<nblk, 256, 0, stream>>>(ids, hist, n_tokens);
    k_scan   <<<1,    256, 0, stream>>>(hist, offs);
    k_scatter<<<nblk, 256, 0, stream>>>(ids, offs, perm, n_tokens);
    compemb_kernel<<<n_tokens, 256, 0, stream>>>(
        perm, ids, tok, op_t, var_t, cst_t, str_t, spc_t, out);
}

// Round 6
// 79.717 us; speedup vs baseline: 2.0193x; 2.0193x over previous
//
#include <hip/hip_runtime.h>

// CompositionalEmbeddings: out[b,s, 0:512]   = token_table[id]
//                          out[b,s, 512:1024] = cat_table[id]
// cat_table = concat(op[10], var[10], const[10], struct[10], special[49960]);
// category start offsets align with id ranges -> direct gather.
//
// Final structure (R3, best = 79.7 us): one 256-thread block per token,
// 16 B per lane, lanes 0-127 token half / 128-255 category half
// (wave-uniform branches), NT stores so the 256 MB write stream doesn't
// evict the ~205 MB of tables from L2/L3.
//
// Tried and rejected with evidence:
//  - R4 4-tokens/block MLP batching: 82.1 us (not latency-bound; TLP ample)
//  - R5 id-bucketed processing order: 161 us (scattered the write stream,
//    added perm->ids->gather dependent chain)
//
// Roofline: 268 MB writes + 268 MB gathered reads in 79.7 us = 6.7 TB/s
// combined, above the 6.29 TB/s D2D copy ceiling (partial L3 service).

typedef float f32x4 __attribute__((ext_vector_type(4)));

#define V4_PER_HALF 128   // 512 floats / 4

__global__ __launch_bounds__(256) void compemb_kernel(
    const int* __restrict__ ids,
    const f32x4* __restrict__ tok,     // [50000][128]
    const f32x4* __restrict__ op_t,    // [10][128]
    const f32x4* __restrict__ var_t,   // [10][128]
    const f32x4* __restrict__ cst_t,   // [10][128]
    const f32x4* __restrict__ str_t,   // [10][128]
    const f32x4* __restrict__ spc_t,   // [49960][128]
    f32x4* __restrict__ out,           // [n_tokens][256]
    int n_tokens)
{
    const int token = blockIdx.x;
    if (token >= n_tokens) return;

    const int id = ids[token];          // block-uniform -> scalar load
    const int t  = threadIdx.x;
    const int e  = t & (V4_PER_HALF - 1);

    const f32x4* src;
    long long row;
    if (t < V4_PER_HALF) {
        src = tok;  row = id;           // waves 0-1: token half
    } else {
        if (id < 10)      { src = op_t;  row = id; }      // waves 2-3
        else if (id < 20) { src = var_t; row = id - 10; }
        else if (id < 30) { src = cst_t; row = id - 20; }
        else if (id < 40) { src = str_t; row = id - 30; }
        else              { src = spc_t; row = id - 40; }
    }

    const f32x4 v = src[row * V4_PER_HALF + e];
    __builtin_nontemporal_store(v, &out[(long long)token * 256 + t]);
}

extern "C" void kernel_launch(void* const* d_in, const int* in_sizes, int n_in,
                              void* d_out, int out_size, void* d_ws, size_t ws_size,
                              hipStream_t stream) {
    const int*   ids   = (const int*)  d_in[0];
    const f32x4* tok   = (const f32x4*)d_in[1];
    const f32x4* op_t  = (const f32x4*)d_in[2];
    const f32x4* var_t = (const f32x4*)d_in[3];
    const f32x4* cst_t = (const f32x4*)d_in[4];
    const f32x4* str_t = (const f32x4*)d_in[5];
    const f32x4* spc_t = (const f32x4*)d_in[6];
    f32x4* out = (f32x4*)d_out;

    const int n_tokens = in_sizes[0];          // 32 * 2048 = 65536
    compemb_kernel<<<n_tokens, 256, 0, stream>>>(
        ids, tok, op_t, var_t, cst_t, str_t, spc_t, out, n_tokens);
}